// Round 8
// baseline (272.068 us; speedup 1.0000x reference)
//
#include <hip/hip_runtime.h>

typedef unsigned short u16;
typedef unsigned char u8;
typedef short bf16x8 __attribute__((ext_vector_type(8)));
typedef float f32x4 __attribute__((ext_vector_type(4)));

#define CH 512
#define HW 4096
#define TOKENS 16384
#define NGRP 32

__device__ __forceinline__ u16 f2bf(float f) {
  unsigned u = __float_as_uint(f);
  u += 0x7fffu + ((u >> 16) & 1u);   // round-nearest-even
  return (u16)(u >> 16);
}
__device__ __forceinline__ float bf2f(u16 h) {
  return __uint_as_float(((unsigned)h) << 16);
}
__device__ __forceinline__ u8 f2fp8(float f) {   // OCP e4m3fn, RNE+sat
  return (u8)(__builtin_amdgcn_cvt_pk_fp8_f32(f, f, 0, false) & 0xff);
}
__device__ __forceinline__ unsigned f2fp8x4(float a, float b, float c, float d) {
  int lo = __builtin_amdgcn_cvt_pk_fp8_f32(a, b, 0, false);
  return (unsigned)__builtin_amdgcn_cvt_pk_fp8_f32(c, d, lo, true);
}

// async global->LDS, 16B per lane; lds base must be wave-uniform
#define GLOAD16(gp, lp)                                                        \
  __builtin_amdgcn_global_load_lds(                                            \
      (const __attribute__((address_space(1))) unsigned int*)(const void*)(gp),\
      (__attribute__((address_space(3))) unsigned int*)(void*)(lp), 16, 0, 0)

// ---------------- GroupNorm stats: one block per (b,g) ----------------
__global__ void gn_stats(const float* __restrict__ x, float2* __restrict__ stats) {
  int bg = blockIdx.x;              // 0..127
  int b = bg >> 5, g = bg & 31;
  const float* base = x + (size_t)b * HW * CH + g * 16;
  float s = 0.f, s2 = 0.f;
  for (int p = threadIdx.x; p < HW; p += 256) {
    const float4* row = (const float4*)(base + (size_t)p * CH);
#pragma unroll
    for (int q = 0; q < 4; ++q) {
      float4 v = row[q];
      s += v.x + v.y + v.z + v.w;
      s2 += v.x * v.x + v.y * v.y + v.z * v.z + v.w * v.w;
    }
  }
#pragma unroll
  for (int o = 32; o; o >>= 1) { s += __shfl_down(s, o); s2 += __shfl_down(s2, o); }
  __shared__ float rs[4], rs2[4];
  int wid = threadIdx.x >> 6, lane = threadIdx.x & 63;
  if (lane == 0) { rs[wid] = s; rs2[wid] = s2; }
  __syncthreads();
  if (threadIdx.x == 0) {
    float S = rs[0] + rs[1] + rs[2] + rs[3];
    float S2 = rs2[0] + rs2[1] + rs2[2] + rs2[3];
    float mean = S * (1.f / 65536.f);
    float var = S2 * (1.f / 65536.f) - mean * mean;
    stats[bg] = make_float2(mean, rsqrtf(var + 1e-5f));
  }
}

// ---------------- GroupNorm apply -> xn (bf16) ----------------
__global__ void gn_apply(const float* __restrict__ x, const float* __restrict__ gamma,
                         const float* __restrict__ beta, const float2* __restrict__ stats,
                         u16* __restrict__ xn) {
  size_t i = (size_t)blockIdx.x * blockDim.x + threadIdx.x;  // chunk of 8 elems
  size_t e0 = i * 8;
  int c = (int)(e0 & (CH - 1));
  size_t t = e0 >> 9;
  int b = (int)(t >> 12);
  float2 st = stats[b * NGRP + (c >> 4)];
  float4 v0 = *(const float4*)(x + t * CH + c);
  float4 v1 = *(const float4*)(x + t * CH + c + 4);
  float4 g0 = *(const float4*)(gamma + c);
  float4 g1 = *(const float4*)(gamma + c + 4);
  float4 b0 = *(const float4*)(beta + c);
  float4 b1 = *(const float4*)(beta + c + 4);
  float o[8];
  o[0] = (v0.x - st.x) * st.y * g0.x + b0.x;
  o[1] = (v0.y - st.x) * st.y * g0.y + b0.y;
  o[2] = (v0.z - st.x) * st.y * g0.z + b0.z;
  o[3] = (v0.w - st.x) * st.y * g0.w + b0.w;
  o[4] = (v1.x - st.x) * st.y * g1.x + b1.x;
  o[5] = (v1.y - st.x) * st.y * g1.y + b1.y;
  o[6] = (v1.z - st.x) * st.y * g1.z + b1.z;
  o[7] = (v1.w - st.x) * st.y * g1.w + b1.w;
  union { u16 us[8]; uint4 q; } pk;
#pragma unroll
  for (int k = 0; k < 8; ++k) pk.us[k] = f2bf(o[k]);
  *(uint4*)(xn + e0) = pk.q;
}

// ---------------- transpose 512x512 weights fp32 -> bf16 (T[d][c] = W[c][d]) ----------------
__global__ void transpose_w(const float* __restrict__ W0, const float* __restrict__ W1,
                            const float* __restrict__ W2, const float* __restrict__ W3,
                            u16* __restrict__ T0, u16* __restrict__ T1,
                            u16* __restrict__ T2, u16* __restrict__ T3) {
  const float* W; u16* T;
  switch (blockIdx.z) {
    case 0: W = W0; T = T0; break;
    case 1: W = W1; T = T1; break;
    case 2: W = W2; T = T2; break;
    default: W = W3; T = T3; break;
  }
  __shared__ float tile[32][33];
  int tx = threadIdx.x, ty = threadIdx.y;
  int x0 = blockIdx.x * 32, y0 = blockIdx.y * 32;
#pragma unroll
  for (int r = 0; r < 32; r += 8) tile[ty + r][tx] = W[(size_t)(y0 + ty + r) * CH + x0 + tx];
  __syncthreads();
#pragma unroll
  for (int r = 0; r < 32; r += 8) T[(size_t)(x0 + ty + r) * CH + y0 + tx] = f2bf(tile[tx][ty + r]);
}

// ---- QKV: bf16 m97 GEMM (global_load_lds), epilogue -> fp8 Q8,K8 rowmajor + V8t transposed ----
__global__ __launch_bounds__(256) void qkv97(const u16* __restrict__ A,
                                             const u16* __restrict__ Bt,
                                             const float* __restrict__ bq,
                                             const float* __restrict__ bk,
                                             const float* __restrict__ bv,
                                             u8* __restrict__ Q8, u8* __restrict__ K8,
                                             u8* __restrict__ V8t) {
  constexpr int BM = 128, BN = 128, BK = 64;
  const int K = CH;
  __shared__ __align__(16) u16 lA[BM * BK];
  __shared__ __align__(16) u16 lB[BN * BK];
  const int tid = threadIdx.x;
  const int lane = tid & 63, wid = tid >> 6;
  const int bm = blockIdx.y * BM, bn = blockIdx.x * BN;
  const int wm = (wid >> 1) * 64, wn = (wid & 1) * 64;
  const int r0 = lane & 15, h = lane >> 4;

  const int srow = lane >> 3, scol = (lane & 7) * 8;
  size_t aoff[4], boff[4];
#pragma unroll
  for (int s = 0; s < 4; ++s) {
    int row = (wid * 4 + s) * 8 + srow;
    aoff[s] = (size_t)(bm + row) * K + scol;
    boff[s] = (size_t)(bn + row) * K + scol;
  }

  f32x4 acc[4][4] = {};
  for (int kt = 0; kt < K; kt += BK) {
    __syncthreads();
#pragma unroll
    for (int s = 0; s < 4; ++s) {
      GLOAD16(A + aoff[s] + kt, &lA[(wid * 4 + s) * 512]);
      GLOAD16(Bt + boff[s] + kt, &lB[(wid * 4 + s) * 512]);
    }
    __syncthreads();
#pragma unroll
    for (int kk = 0; kk < BK; kk += 32) {
      bf16x8 af[4], bfr[4];
#pragma unroll
      for (int i = 0; i < 4; ++i)
        af[i] = *(const bf16x8*)(&lA[(wm + i * 16 + r0) * BK + kk + h * 8]);
#pragma unroll
      for (int j = 0; j < 4; ++j)
        bfr[j] = *(const bf16x8*)(&lB[(wn + j * 16 + r0) * BK + kk + h * 8]);
#pragma unroll
      for (int i = 0; i < 4; ++i)
#pragma unroll
        for (int j = 0; j < 4; ++j)
          acc[i][j] = __builtin_amdgcn_mfma_f32_16x16x32_bf16(af[i], bfr[j], acc[i][j], 0, 0, 0);
    }
  }

#pragma unroll
  for (int j = 0; j < 4; ++j) {
    int n = bn + wn + j * 16 + r0;
    int nn = n & 511, ch = n >> 9;
    float bvv = ch == 0 ? bq[nn] : ch == 1 ? bk[nn] : bv[nn];
#pragma unroll
    for (int i = 0; i < 4; ++i) {
      int m0 = bm + wm + i * 16 + h * 4;
      float v[4];
#pragma unroll
      for (int r = 0; r < 4; ++r) v[r] = acc[i][j][r] + bvv;
      if (ch == 2) {                  // V: transposed fp8 [bb][CH][HW], pack 4 rows
        int bb = m0 >> 12, tl = m0 & (HW - 1);
        *(unsigned*)(V8t + ((size_t)bb * CH + nn) * HW + tl) =
            f2fp8x4(v[0], v[1], v[2], v[3]);
      } else {
        u8* P = ch == 0 ? Q8 : K8;
#pragma unroll
        for (int r = 0; r < 4; ++r) P[(size_t)(m0 + r) * CH + nn] = f2fp8(v[r]);
      }
    }
  }
}

// ---- fp8 2-phase double-buffered gload_lds GEMM, 128x128 tile, BK=64, 4 waves ----
// LDS rows 64B linear; swizzle: col16 ^= ((row>>1)&3)<<4 applied on global SOURCE +
// on frag READ (involution; gload_lds dest stays linear). Banks: 2 lanes/bank = free.
// Schedule per K-tile: STAGE(buf^1,t+1) issued BEFORE compute(buf,t); vmcnt(0)+barrier.
// MODE 5: S = fp8(exp(scale*Q K^T)) + partial rowsums -> lsum_out[(z*64+bx*2+half)*HW+row]
// MODE 4: O = (S V^T)/rowsum (bf16 out); XCD-swizzled 1-D grid when gridDim.y==1
template <int MODE>
__global__ __launch_bounds__(256) void gemm8p(const u8* __restrict__ A,
                                              const u8* __restrict__ Bt,
                                              const float* __restrict__ lsum_in,
                                              float* __restrict__ lsum_out,
                                              void* __restrict__ Cout,
                                              int N, int K, float scale,
                                              size_t sA, size_t sB, size_t sC) {
  __shared__ __align__(16) u8 LA[2][8192];
  __shared__ __align__(16) u8 LB[2][8192];
  __shared__ float lsum_sh[(MODE == 4) ? 128 : 1];

  int bm, bn, z;
  if constexpr (MODE == 4) {
    if (gridDim.y == 1) {             // big path: 512 blocks, XCD-chunked swizzle
      int p = blockIdx.x;
      int xcd = p & 7, j = p >> 3;    // j: 0..63 per XCD
      int xi = j & 3;                 // 4 consecutive same-XCD blocks share m-panel
      int mp = xcd * 16 + (j >> 2);   // global m-panel 0..127
      bn = xi * 128; bm = (mp & 31) * 128; z = mp >> 5;
    } else {
      z = blockIdx.z; bm = blockIdx.y * 128; bn = blockIdx.x * 128;
    }
  } else {
    z = blockIdx.z; bm = blockIdx.y * 128; bn = blockIdx.x * 128;
  }
  A += (size_t)z * sA;
  Bt += (size_t)z * sB;

  const int tid = threadIdx.x, lane = tid & 63, wid = tid >> 6;
  const int wm = (wid >> 1) * 64, wn = (wid & 1) * 64;
  const int r0 = lane & 15, h = lane >> 4, h8 = h * 8;
  const int rsw = ((r0 >> 1) & 3) << 4;     // read-side swizzle

  if constexpr (MODE == 4) {
    // pre-pass: true row sums = sum of 64 partials per row
    if (tid < 128) {
      const float* lp = lsum_in + (size_t)(z * 64) * HW + bm + tid;
      float s = 0.f;
#pragma unroll 8
      for (int p = 0; p < 64; ++p) s += lp[(size_t)p * HW];
      lsum_sh[tid] = s;
    }
  }

  // staging sources: thread tid covers 16B of rows {tid>>2, 64+tid>>2} per operand;
  // source col pre-swizzled so the linear LDS dest realizes the swizzled layout.
  const int srow = tid >> 2;
  const int scol = ((tid & 3) * 16) ^ (((tid >> 3) & 3) << 4);
  const u8* aP0 = A + (size_t)(bm + srow) * K + scol;
  const u8* aP1 = A + (size_t)(bm + 64 + srow) * K + scol;
  const u8* bP0 = Bt + (size_t)(bn + srow) * K + scol;
  const u8* bP1 = Bt + (size_t)(bn + 64 + srow) * K + scol;

  f32x4 acc[4][4] = {};

#define STG(bu, kt) do {                                            \
    GLOAD16(aP0 + (size_t)(kt) * 64, &LA[bu][wid * 1024]);          \
    GLOAD16(aP1 + (size_t)(kt) * 64, &LA[bu][4096 + wid * 1024]);   \
    GLOAD16(bP0 + (size_t)(kt) * 64, &LB[bu][wid * 1024]);          \
    GLOAD16(bP1 + (size_t)(kt) * 64, &LB[bu][4096 + wid * 1024]);   \
  } while (0)

#define CMP(bu) do {                                                           \
    _Pragma("unroll")                                                          \
    for (int kk = 0; kk < 64; kk += 32) {                                      \
      long af_[4], bf_[4];                                                     \
      _Pragma("unroll")                                                        \
      for (int i = 0; i < 4; ++i)                                              \
        af_[i] = *(const long*)(&LA[bu][(wm + i * 16 + r0) * 64 +              \
                                        ((kk + h8) ^ rsw)]);                   \
      _Pragma("unroll")                                                        \
      for (int j = 0; j < 4; ++j)                                              \
        bf_[j] = *(const long*)(&LB[bu][(wn + j * 16 + r0) * 64 +              \
                                        ((kk + h8) ^ rsw)]);                   \
      _Pragma("unroll")                                                        \
      for (int i = 0; i < 4; ++i)                                              \
        _Pragma("unroll")                                                      \
        for (int j = 0; j < 4; ++j)                                            \
          acc[i][j] = __builtin_amdgcn_mfma_f32_16x16x32_fp8_fp8(              \
              af_[i], bf_[j], acc[i][j], 0, 0, 0);                             \
    }                                                                          \
  } while (0)

#define VMB do {                                          \
    asm volatile("s_waitcnt vmcnt(0)" ::: "memory");      \
    __builtin_amdgcn_s_barrier();                         \
    __builtin_amdgcn_sched_barrier(0);                    \
  } while (0)

  const int nt = K >> 6;
  STG(0, 0);
  VMB;
  for (int t = 0; t < nt; t += 2) {
    STG(1, t + 1);
    CMP(0);
    VMB;
    if (t + 2 < nt) STG(0, t + 2);
    CMP(1);
    VMB;
  }

#undef STG
#undef CMP
#undef VMB

  // epilogue: D layout col(n)=lane&15, row=(lane>>4)*4+r
  if constexpr (MODE == 5) {
    u8* C = (u8*)Cout + (size_t)z * sC;
    float* lp = lsum_out + (size_t)(z * 64 + blockIdx.x * 2 + (wid & 1)) * HW;
#pragma unroll
    for (int i = 0; i < 4; ++i) {
      int m0 = bm + wm + i * 16 + h * 4;
      float rs[4] = {0.f, 0.f, 0.f, 0.f};
#pragma unroll
      for (int j = 0; j < 4; ++j) {
        int n = bn + wn + j * 16 + r0;
#pragma unroll
        for (int r = 0; r < 4; ++r) {
          float e = __expf(acc[i][j][r] * scale);
          rs[r] += e;
          C[(size_t)(m0 + r) * N + n] = f2fp8(e);
        }
      }
#pragma unroll
      for (int r = 0; r < 4; ++r) {
#pragma unroll
        for (int w = 1; w < 16; w <<= 1) rs[r] += __shfl_xor(rs[r], w);
        if (r0 == 0) lp[m0 + r] = rs[r];
      }
    }
  } else {
    u16* C = (u16*)Cout + (size_t)z * sC;
#pragma unroll
    for (int j = 0; j < 4; ++j) {
      int n = bn + wn + j * 16 + r0;
#pragma unroll
      for (int i = 0; i < 4; ++i) {
        int m0 = bm + wm + i * 16 + h * 4;
#pragma unroll
        for (int r = 0; r < 4; ++r) {
          float inv = 1.0f / lsum_sh[wm + i * 16 + h * 4 + r];
          C[(size_t)(m0 + r) * N + n] = f2bf(acc[i][j][r] * inv);
        }
      }
    }
  }
}

// ---- proj: bf16 m97 GEMM, f32 out + residual ----
__global__ __launch_bounds__(256) void proj97(const u16* __restrict__ A,
                                              const u16* __restrict__ Bt,
                                              const float* __restrict__ bias,
                                              const float* __restrict__ residual,
                                              float* __restrict__ Cout) {
  constexpr int BM = 128, BN = 128, BK = 64;
  const int K = CH, N = CH;
  __shared__ __align__(16) u16 lA[BM * BK];
  __shared__ __align__(16) u16 lB[BN * BK];
  const int tid = threadIdx.x;
  const int lane = tid & 63, wid = tid >> 6;
  const int bm = blockIdx.y * BM, bn = blockIdx.x * BN;
  const int wm = (wid >> 1) * 64, wn = (wid & 1) * 64;
  const int r0 = lane & 15, h = lane >> 4;

  const int srow = lane >> 3, scol = (lane & 7) * 8;
  size_t aoff[4], boff[4];
#pragma unroll
  for (int s = 0; s < 4; ++s) {
    int row = (wid * 4 + s) * 8 + srow;
    aoff[s] = (size_t)(bm + row) * K + scol;
    boff[s] = (size_t)(bn + row) * K + scol;
  }

  f32x4 acc[4][4] = {};
  for (int kt = 0; kt < K; kt += BK) {
    __syncthreads();
#pragma unroll
    for (int s = 0; s < 4; ++s) {
      GLOAD16(A + aoff[s] + kt, &lA[(wid * 4 + s) * 512]);
      GLOAD16(Bt + boff[s] + kt, &lB[(wid * 4 + s) * 512]);
    }
    __syncthreads();
#pragma unroll
    for (int kk = 0; kk < BK; kk += 32) {
      bf16x8 af[4], bfr[4];
#pragma unroll
      for (int i = 0; i < 4; ++i)
        af[i] = *(const bf16x8*)(&lA[(wm + i * 16 + r0) * BK + kk + h * 8]);
#pragma unroll
      for (int j = 0; j < 4; ++j)
        bfr[j] = *(const bf16x8*)(&lB[(wn + j * 16 + r0) * BK + kk + h * 8]);
#pragma unroll
      for (int i = 0; i < 4; ++i)
#pragma unroll
        for (int j = 0; j < 4; ++j)
          acc[i][j] = __builtin_amdgcn_mfma_f32_16x16x32_bf16(af[i], bfr[j], acc[i][j], 0, 0, 0);
    }
  }

#pragma unroll
  for (int j = 0; j < 4; ++j) {
    int n = bn + wn + j * 16 + r0;
    float bvv = bias[n];
#pragma unroll
    for (int i = 0; i < 4; ++i) {
      int m0 = bm + wm + i * 16 + h * 4;
#pragma unroll
      for (int r = 0; r < 4; ++r) {
        size_t idx = (size_t)(m0 + r) * N + n;
        Cout[idx] = acc[i][j][r] + bvv + residual[idx];
      }
    }
  }
}

extern "C" void kernel_launch(void* const* d_in, const int* in_sizes, int n_in,
                              void* d_out, int out_size, void* d_ws, size_t ws_size,
                              hipStream_t stream) {
  (void)in_sizes; (void)n_in; (void)out_size;
  const float* x     = (const float*)d_in[0];
  const float* gamma = (const float*)d_in[1];
  const float* beta  = (const float*)d_in[2];
  const float* Wq    = (const float*)d_in[3];
  const float* bq    = (const float*)d_in[4];
  const float* Wk    = (const float*)d_in[5];
  const float* bk    = (const float*)d_in[6];
  const float* Wv    = (const float*)d_in[7];
  const float* bv    = (const float*)d_in[8];
  const float* Wp    = (const float*)d_in[9];
  const float* bp    = (const float*)d_in[10];
  float* out = (float*)d_out;

  char* ws = (char*)d_ws;
  size_t off = 0;
  auto alloc = [&](size_t bytes) -> void* {
    void* p = ws + off;
    off += (bytes + 255) & ~(size_t)255;
    return p;
  };
  const size_t XN  = (size_t)TOKENS * CH * 2;     // 16 MB bf16
  const size_t X8  = (size_t)TOKENS * CH;         // 8 MB fp8
  const size_t WT  = (size_t)CH * CH * 2;         // 0.5 MB
  const size_t S8B = (size_t)HW * HW;             // 16.8 MB fp8 per batch
  const size_t LS  = (size_t)4 * 64 * HW * sizeof(float);  // 4 MB partial rowsums
  const size_t need_all = 1024 * 1024 + LS + 2 * XN + 3 * X8 + 4 * WT + 4 * S8B;
  const bool big = ws_size >= need_all;           // deterministic across calls

  float2* stats    = (float2*)alloc(128 * sizeof(float2));
  float* lsum_part = (float*)alloc(LS);           // [z][64][HW]
  u16* xn   = (u16*)alloc(XN);
  u16* Ob   = (u16*)alloc(XN);
  u8*  Q8   = (u8*)alloc(X8);    // [B*HW][CH] fp8
  u8*  K8   = (u8*)alloc(X8);
  u8*  V8t  = (u8*)alloc(X8);    // [B][CH][HW] fp8
  u16* Wqkv = (u16*)alloc(3 * WT);  // [Wq^T; Wk^T; Wv^T] stacked along rows
  u16* WpT  = (u16*)alloc(WT);
  u8*  S8   = (u8*)alloc(big ? 4 * S8B : S8B);    // exp'd scores fp8

  gn_stats<<<128, 256, 0, stream>>>(x, stats);
  gn_apply<<<TOKENS * CH / 8 / 256, 256, 0, stream>>>(x, gamma, beta, stats, xn);
  transpose_w<<<dim3(16, 16, 4), dim3(32, 8), 0, stream>>>(
      Wq, Wk, Wv, Wp, Wqkv, Wqkv + (size_t)CH * CH, Wqkv + 2 * (size_t)CH * CH, WpT);

  qkv97<<<dim3(1536 / 128, TOKENS / 128), 256, 0, stream>>>(
      xn, Wqkv, bq, bk, bv, Q8, K8, V8t);

  const float scl = 0.044194173824159216f;  // 1/sqrt(512)
  if (big) {
    gemm8p<5><<<dim3(32, 32, 4), 256, 0, stream>>>(
        Q8, K8, nullptr, lsum_part, S8, HW, CH, scl,
        (size_t)HW * CH, (size_t)HW * CH, (size_t)HW * HW);
    gemm8p<4><<<dim3(512, 1, 1), 256, 0, stream>>>(
        S8, V8t, lsum_part, nullptr, Ob, CH, HW, 1.0f,
        (size_t)HW * HW, (size_t)CH * HW, (size_t)HW * CH);
  } else {
    for (int b = 0; b < 4; ++b) {
      gemm8p<5><<<dim3(32, 32, 1), 256, 0, stream>>>(
          Q8 + (size_t)b * HW * CH, K8 + (size_t)b * HW * CH,
          nullptr, lsum_part + (size_t)b * 64 * HW, S8, HW, CH, scl, 0, 0, 0);
      gemm8p<4><<<dim3(4, 32, 1), 256, 0, stream>>>(
          S8, V8t + (size_t)b * CH * HW, lsum_part + (size_t)b * 64 * HW,
          nullptr, Ob + (size_t)b * HW * CH, CH, HW, 1.0f, 0, 0, 0);
    }
  }

  proj97<<<dim3(CH / 128, TOKENS / 128), 256, 0, stream>>>(Ob, WpT, bp, x, out);
}

// Round 9
// 257.508 us; speedup vs baseline: 1.0565x; 1.0565x over previous
//
#include <hip/hip_runtime.h>

typedef unsigned short u16;
typedef unsigned char u8;
typedef short bf16x8 __attribute__((ext_vector_type(8)));
typedef float f32x4 __attribute__((ext_vector_type(4)));

#define CH 512
#define HW 4096
#define TOKENS 16384
#define NGRP 32

__device__ __forceinline__ u16 f2bf(float f) {
  unsigned u = __float_as_uint(f);
  u += 0x7fffu + ((u >> 16) & 1u);   // round-nearest-even
  return (u16)(u >> 16);
}
__device__ __forceinline__ float bf2f(u16 h) {
  return __uint_as_float(((unsigned)h) << 16);
}
__device__ __forceinline__ u8 f2fp8(float f) {   // OCP e4m3fn, RNE+sat
  return (u8)(__builtin_amdgcn_cvt_pk_fp8_f32(f, f, 0, false) & 0xff);
}
__device__ __forceinline__ unsigned f2fp8x4(float a, float b, float c, float d) {
  int lo = __builtin_amdgcn_cvt_pk_fp8_f32(a, b, 0, false);
  return (unsigned)__builtin_amdgcn_cvt_pk_fp8_f32(c, d, lo, true);
}

// async global->LDS, 16B per lane; lds base must be wave-uniform (HW scatters lane*16)
#define GLOAD16(gp, lp)                                                        \
  __builtin_amdgcn_global_load_lds(                                            \
      (const __attribute__((address_space(1))) unsigned int*)(const void*)(gp),\
      (__attribute__((address_space(3))) unsigned int*)(void*)(lp), 16, 0, 0)

// ---------------- GroupNorm stats: one block per (b,g) ----------------
__global__ void gn_stats(const float* __restrict__ x, float2* __restrict__ stats) {
  int bg = blockIdx.x;              // 0..127
  int b = bg >> 5, g = bg & 31;
  const float* base = x + (size_t)b * HW * CH + g * 16;
  float s = 0.f, s2 = 0.f;
  for (int p = threadIdx.x; p < HW; p += 256) {
    const float4* row = (const float4*)(base + (size_t)p * CH);
#pragma unroll
    for (int q = 0; q < 4; ++q) {
      float4 v = row[q];
      s += v.x + v.y + v.z + v.w;
      s2 += v.x * v.x + v.y * v.y + v.z * v.z + v.w * v.w;
    }
  }
#pragma unroll
  for (int o = 32; o; o >>= 1) { s += __shfl_down(s, o); s2 += __shfl_down(s2, o); }
  __shared__ float rs[4], rs2[4];
  int wid = threadIdx.x >> 6, lane = threadIdx.x & 63;
  if (lane == 0) { rs[wid] = s; rs2[wid] = s2; }
  __syncthreads();
  if (threadIdx.x == 0) {
    float S = rs[0] + rs[1] + rs[2] + rs[3];
    float S2 = rs2[0] + rs2[1] + rs2[2] + rs2[3];
    float mean = S * (1.f / 65536.f);
    float var = S2 * (1.f / 65536.f) - mean * mean;
    stats[bg] = make_float2(mean, rsqrtf(var + 1e-5f));
  }
}

// ---------------- GroupNorm apply -> xn (bf16) ----------------
__global__ void gn_apply(const float* __restrict__ x, const float* __restrict__ gamma,
                         const float* __restrict__ beta, const float2* __restrict__ stats,
                         u16* __restrict__ xn) {
  size_t i = (size_t)blockIdx.x * blockDim.x + threadIdx.x;  // chunk of 8 elems
  size_t e0 = i * 8;
  int c = (int)(e0 & (CH - 1));
  size_t t = e0 >> 9;
  int b = (int)(t >> 12);
  float2 st = stats[b * NGRP + (c >> 4)];
  float4 v0 = *(const float4*)(x + t * CH + c);
  float4 v1 = *(const float4*)(x + t * CH + c + 4);
  float4 g0 = *(const float4*)(gamma + c);
  float4 g1 = *(const float4*)(gamma + c + 4);
  float4 b0 = *(const float4*)(beta + c);
  float4 b1 = *(const float4*)(beta + c + 4);
  float o[8];
  o[0] = (v0.x - st.x) * st.y * g0.x + b0.x;
  o[1] = (v0.y - st.x) * st.y * g0.y + b0.y;
  o[2] = (v0.z - st.x) * st.y * g0.z + b0.z;
  o[3] = (v0.w - st.x) * st.y * g0.w + b0.w;
  o[4] = (v1.x - st.x) * st.y * g1.x + b1.x;
  o[5] = (v1.y - st.x) * st.y * g1.y + b1.y;
  o[6] = (v1.z - st.x) * st.y * g1.z + b1.z;
  o[7] = (v1.w - st.x) * st.y * g1.w + b1.w;
  union { u16 us[8]; uint4 q; } pk;
#pragma unroll
  for (int k = 0; k < 8; ++k) pk.us[k] = f2bf(o[k]);
  *(uint4*)(xn + e0) = pk.q;
}

// ---------------- transpose 512x512 weights fp32 -> bf16 (T[d][c] = W[c][d]) ----------------
__global__ void transpose_w(const float* __restrict__ W0, const float* __restrict__ W1,
                            const float* __restrict__ W2, const float* __restrict__ W3,
                            u16* __restrict__ T0, u16* __restrict__ T1,
                            u16* __restrict__ T2, u16* __restrict__ T3) {
  const float* W; u16* T;
  switch (blockIdx.z) {
    case 0: W = W0; T = T0; break;
    case 1: W = W1; T = T1; break;
    case 2: W = W2; T = T2; break;
    default: W = W3; T = T3; break;
  }
  __shared__ float tile[32][33];
  int tx = threadIdx.x, ty = threadIdx.y;
  int x0 = blockIdx.x * 32, y0 = blockIdx.y * 32;
#pragma unroll
  for (int r = 0; r < 32; r += 8) tile[ty + r][tx] = W[(size_t)(y0 + ty + r) * CH + x0 + tx];
  __syncthreads();
#pragma unroll
  for (int r = 0; r < 32; r += 8) T[(size_t)(x0 + ty + r) * CH + y0 + tx] = f2bf(tile[tx][ty + r]);
}

// ---- QKV: bf16 m97 GEMM (global_load_lds), epilogue -> fp8 Q8,K8 rowmajor + V8t transposed ----
__global__ __launch_bounds__(256) void qkv97(const u16* __restrict__ A,
                                             const u16* __restrict__ Bt,
                                             const float* __restrict__ bq,
                                             const float* __restrict__ bk,
                                             const float* __restrict__ bv,
                                             u8* __restrict__ Q8, u8* __restrict__ K8,
                                             u8* __restrict__ V8t) {
  constexpr int BM = 128, BN = 128, BK = 64;
  const int K = CH;
  __shared__ __align__(16) u16 lA[BM * BK];
  __shared__ __align__(16) u16 lB[BN * BK];
  const int tid = threadIdx.x;
  const int lane = tid & 63, wid = tid >> 6;
  const int bm = blockIdx.y * BM, bn = blockIdx.x * BN;
  const int wm = (wid >> 1) * 64, wn = (wid & 1) * 64;
  const int r0 = lane & 15, h = lane >> 4;

  const int srow = lane >> 3, scol = (lane & 7) * 8;
  size_t aoff[4], boff[4];
#pragma unroll
  for (int s = 0; s < 4; ++s) {
    int row = (wid * 4 + s) * 8 + srow;
    aoff[s] = (size_t)(bm + row) * K + scol;
    boff[s] = (size_t)(bn + row) * K + scol;
  }

  f32x4 acc[4][4] = {};
  for (int kt = 0; kt < K; kt += BK) {
    __syncthreads();
#pragma unroll
    for (int s = 0; s < 4; ++s) {
      GLOAD16(A + aoff[s] + kt, &lA[(wid * 4 + s) * 512]);
      GLOAD16(Bt + boff[s] + kt, &lB[(wid * 4 + s) * 512]);
    }
    __syncthreads();
#pragma unroll
    for (int kk = 0; kk < BK; kk += 32) {
      bf16x8 af[4], bfr[4];
#pragma unroll
      for (int i = 0; i < 4; ++i)
        af[i] = *(const bf16x8*)(&lA[(wm + i * 16 + r0) * BK + kk + h * 8]);
#pragma unroll
      for (int j = 0; j < 4; ++j)
        bfr[j] = *(const bf16x8*)(&lB[(wn + j * 16 + r0) * BK + kk + h * 8]);
#pragma unroll
      for (int i = 0; i < 4; ++i)
#pragma unroll
        for (int j = 0; j < 4; ++j)
          acc[i][j] = __builtin_amdgcn_mfma_f32_16x16x32_bf16(af[i], bfr[j], acc[i][j], 0, 0, 0);
    }
  }

#pragma unroll
  for (int j = 0; j < 4; ++j) {
    int n = bn + wn + j * 16 + r0;
    int nn = n & 511, ch = n >> 9;
    float bvv = ch == 0 ? bq[nn] : ch == 1 ? bk[nn] : bv[nn];
#pragma unroll
    for (int i = 0; i < 4; ++i) {
      int m0 = bm + wm + i * 16 + h * 4;
      float v[4];
#pragma unroll
      for (int r = 0; r < 4; ++r) v[r] = acc[i][j][r] + bvv;
      if (ch == 2) {                  // V: transposed fp8 [bb][CH][HW], pack 4 rows
        int bb = m0 >> 12, tl = m0 & (HW - 1);
        *(unsigned*)(V8t + ((size_t)bb * CH + nn) * HW + tl) =
            f2fp8x4(v[0], v[1], v[2], v[3]);
      } else {
        u8* P = ch == 0 ? Q8 : K8;
#pragma unroll
        for (int r = 0; r < 4; ++r) P[(size_t)(m0 + r) * CH + nn] = f2fp8(v[r]);
      }
    }
  }
}

// ---- S-GEMM fp8 (R6-proven): S8 = fp8(exp(scale * Q8 K8^T)), partial rowsums ----
__global__ __launch_bounds__(256) void sgemm8(const u8* __restrict__ A,
                                              const u8* __restrict__ Bt,
                                              float* __restrict__ lsum,
                                              u8* __restrict__ S8,
                                              int M, int N, int K, float scale,
                                              size_t sA, size_t sB, size_t sC) {
  constexpr int BM = 128, BN = 128, BK = 64, LRB = 80;
  __shared__ __align__(16) u8 lA[BM * LRB];
  __shared__ __align__(16) u8 lB[BN * LRB];
  const int z = blockIdx.z;
  A += (size_t)z * sA;
  Bt += (size_t)z * sB;
  const int tid = threadIdx.x;
  const int lane = tid & 63, wid = tid >> 6;
  const int bm = blockIdx.y * BM, bn = blockIdx.x * BN;
  const int wm = (wid >> 1) * 64, wn = (wid & 1) * 64;
  const int r0 = lane & 15, h = lane >> 4;

  f32x4 acc[4][4] = {};
  for (int kt = 0; kt < K; kt += BK) {
    __syncthreads();
#pragma unroll
    for (int s = 0; s < 2; ++s) {
      int cid = tid + s * 256;
      int row = cid >> 2, col = (cid & 3) * 16;
      *(uint4*)(&lA[row * LRB + col]) =
          *(const uint4*)(A + (size_t)(bm + row) * K + kt + col);
      *(uint4*)(&lB[row * LRB + col]) =
          *(const uint4*)(Bt + (size_t)(bn + row) * K + kt + col);
    }
    __syncthreads();
#pragma unroll
    for (int kk = 0; kk < BK; kk += 32) {
      long af[4], bfr[4];
#pragma unroll
      for (int i = 0; i < 4; ++i)
        af[i] = *(const long*)(&lA[(wm + i * 16 + r0) * LRB + kk + h * 8]);
#pragma unroll
      for (int j = 0; j < 4; ++j)
        bfr[j] = *(const long*)(&lB[(wn + j * 16 + r0) * LRB + kk + h * 8]);
#pragma unroll
      for (int i = 0; i < 4; ++i)
#pragma unroll
        for (int j = 0; j < 4; ++j)
          acc[i][j] = __builtin_amdgcn_mfma_f32_16x16x32_fp8_fp8(af[i], bfr[j], acc[i][j], 0, 0, 0);
    }
  }

  u8* C = S8 + (size_t)z * sC;
  float* lp = lsum + (size_t)(z * 64 + blockIdx.x * 2 + (wid & 1)) * HW;
#pragma unroll
  for (int i = 0; i < 4; ++i) {
    int m0 = bm + wm + i * 16 + h * 4;
    float rs[4] = {0.f, 0.f, 0.f, 0.f};
#pragma unroll
    for (int j = 0; j < 4; ++j) {
      int n = bn + wn + j * 16 + r0;
#pragma unroll
      for (int r = 0; r < 4; ++r) {
        float e = __expf(acc[i][j][r] * scale);
        rs[r] += e;
        C[(size_t)(m0 + r) * N + n] = f2fp8(e);
      }
    }
#pragma unroll
    for (int r = 0; r < 4; ++r) {
#pragma unroll
      for (int w = 1; w < 16; w <<= 1) rs[r] += __shfl_xor(rs[r], w);
      if (r0 == 0) lp[m0 + r] = rs[r];
    }
  }
}

// ---- PV fp8 DEEP PIPELINE (8-phase-style, counted vmcnt): O = (S8 V8t^T)/rowsum ----
// BM=256 x BN=128, BK=64, 8 waves (2m x 4n), 4 LDS buffers, stage 3 tiles ahead,
// vmcnt(6) in steady state (3 gload_lds per wave per tile: A0,A1,B).
// Swizzle: 16B-granule XOR ((row>>1)&3) on global SOURCE + on frag READ (involution).
__global__ __launch_bounds__(512, 2) void pv8w(const u8* __restrict__ S8,
                                               const u8* __restrict__ V8t,
                                               const float* __restrict__ lsum_in,
                                               u16* __restrict__ Ob) {
  __shared__ __align__(16) u8 LA[4][16384];   // 256 rows x 64B per buf
  __shared__ __align__(16) u8 LB[4][8192];    // 128 rows x 64B per buf
  __shared__ float lsum_sh[256];

  // 256 blocks, XCD-chunked: 4 consecutive same-XCD blocks share one m-panel (S rows)
  const int p = blockIdx.x;
  const int xcd = p & 7, jj = p >> 3;     // jj 0..31
  const int xi = jj & 3;                  // n-block 0..3
  const int mp = xcd * 8 + (jj >> 2);     // m-panel 0..63
  const int bn = xi * 128;
  const int bm = (mp & 15) * 256;
  const int z = mp >> 4;

  const u8* A = S8 + (size_t)z * HW * HW;
  const u8* Bt = V8t + (size_t)z * CH * HW;
  u16* C = Ob + (size_t)z * HW * CH;
  const float* lsum = lsum_in + (size_t)z * 64 * HW;

  const int tid = threadIdx.x, lane = tid & 63, wid = tid >> 6;
  const int wm = (wid >> 2) * 128, wn = (wid & 3) * 32;
  const int r0 = lane & 15, h = lane >> 4, h8 = h * 8;
  const int rsw = ((r0 >> 1) & 3) << 4;

  // pre-pass: true row sums (64 partials per row); drained before the counted pipeline
  if (tid < 256) {
    const float* lp = lsum + bm + tid;
    float s = 0.f;
#pragma unroll 8
    for (int q = 0; q < 64; ++q) s += lp[(size_t)q * HW];
    lsum_sh[tid] = s;
  }
  asm volatile("s_waitcnt vmcnt(0)" ::: "memory");

  // staging geometry: lane covers 16B; source col pre-swizzled so linear LDS dest
  // realizes the swizzled layout (gload_lds scatters lane*16 from uniform base).
  const int sr = lane >> 2;
  const int sc = ((lane & 3) * 16) ^ (((lane >> 3) & 3) << 4);
  const u8* aS0 = A + (size_t)(bm + wid * 32 + sr) * HW + sc;
  const u8* aS1 = aS0 + (size_t)16 * HW;
  const u8* bS  = Bt + (size_t)(bn + wid * 16 + sr) * HW + sc;
  const unsigned adst = wid * 2048;
  const unsigned bdst = wid * 1024;

  f32x4 acc[8][2] = {};

#define STG_A(b, t) do {                                       \
    GLOAD16(aS0 + (size_t)(t) * 64, &LA[b][adst]);             \
    GLOAD16(aS1 + (size_t)(t) * 64, &LA[b][adst + 1024]);      \
  } while (0)
#define STG_B(b, t) GLOAD16(bS + (size_t)(t) * 64, &LB[b][bdst])

#define PHASE(rb, kk, STGSTUFF, ENDSYNC) do {                                   \
    const int ko = ((kk) + h8) ^ rsw;                                           \
    long bf0 = *(const long*)(&LB[rb][(wn + r0) * 64 + ko]);                    \
    long bf1 = *(const long*)(&LB[rb][(wn + 16 + r0) * 64 + ko]);               \
    long af[8];                                                                 \
    _Pragma("unroll")                                                           \
    for (int i_ = 0; i_ < 8; ++i_)                                              \
      af[i_] = *(const long*)(&LA[rb][(wm + i_ * 16 + r0) * 64 + ko]);          \
    STGSTUFF;                                                                   \
    __builtin_amdgcn_s_barrier();                                               \
    asm volatile("s_waitcnt lgkmcnt(0)" ::: "memory");                          \
    __builtin_amdgcn_sched_barrier(0);                                          \
    __builtin_amdgcn_s_setprio(1);                                              \
    _Pragma("unroll")                                                           \
    for (int i_ = 0; i_ < 8; ++i_) {                                            \
      acc[i_][0] = __builtin_amdgcn_mfma_f32_16x16x32_fp8_fp8(af[i_], bf0,      \
                                                              acc[i_][0], 0, 0, 0); \
      acc[i_][1] = __builtin_amdgcn_mfma_f32_16x16x32_fp8_fp8(af[i_], bf1,      \
                                                              acc[i_][1], 0, 0, 0); \
    }                                                                           \
    __builtin_amdgcn_s_setprio(0);                                              \
    ENDSYNC;                                                                    \
  } while (0)

#define BAR __builtin_amdgcn_s_barrier()
#define ENDVM(n) do {                                          \
    asm volatile("s_waitcnt vmcnt(" #n ")" ::: "memory");      \
    __builtin_amdgcn_s_barrier();                              \
    __builtin_amdgcn_sched_barrier(0);                         \
  } while (0)

  // prologue: stage tiles 0,1,2 (9 loads/wave); wait until tile0's 3 landed
  STG_A(0, 0); STG_B(0, 0);
  STG_A(1, 1); STG_B(1, 1);
  STG_A(2, 2); STG_B(2, 2);
  ENDVM(6);

  // steady: 64 K-tiles; during tile t stage t+3; never drain below 6 in-loop
#pragma unroll 1
  for (int t = 0; t < 61; ++t) {
    const int rb = t & 3, sb = (t + 3) & 3;
    PHASE(rb, 0, STG_A(sb, t + 3), BAR);
    PHASE(rb, 32, STG_B(sb, t + 3), ENDVM(6));
  }
  PHASE(1, 0, , BAR);                 // t=61
  PHASE(1, 32, , ENDVM(3));
  PHASE(2, 0, , BAR);                 // t=62
  PHASE(2, 32, , ENDVM(0));
  PHASE(3, 0, , BAR);                 // t=63
  PHASE(3, 32, , );

#undef STG_A
#undef STG_B
#undef PHASE
#undef BAR
#undef ENDVM

  // epilogue: D layout col(n)=lane&15, row=(lane>>4)*4+r; divide by rowsum
#pragma unroll
  for (int i = 0; i < 8; ++i) {
    int lrow = wm + i * 16 + h * 4;
#pragma unroll
    for (int r = 0; r < 4; ++r) {
      float inv = 1.0f / lsum_sh[lrow + r];
      size_t rowoff = (size_t)(bm + lrow + r) * CH;
#pragma unroll
      for (int j = 0; j < 2; ++j)
        C[rowoff + bn + wn + j * 16 + r0] = f2bf(acc[i][j][r] * inv);
    }
  }
}

// ---- PV fp8 fallback (R6 reg-staged), used when ws is small ----
__global__ __launch_bounds__(256) void pv8(const u8* __restrict__ A,
                                           const u8* __restrict__ Bt,
                                           const float* __restrict__ lsum,
                                           u16* __restrict__ Ob,
                                           int M, int N, int K,
                                           size_t sA, size_t sB, size_t sC) {
  constexpr int BM = 128, BN = 128, BK = 64, LRB = 80;
  __shared__ __align__(16) u8 lA[BM * LRB];
  __shared__ __align__(16) u8 lB[BN * LRB];
  __shared__ float lsum_sh[BM];

  int bm, bn, z;
  z = blockIdx.z; bm = blockIdx.y * BM; bn = blockIdx.x * BN;
  A += (size_t)z * sA;
  Bt += (size_t)z * sB;
  const int tid = threadIdx.x;
  const int lane = tid & 63, wid = tid >> 6;
  const int wm = (wid >> 1) * 64, wn = (wid & 1) * 64;
  const int r0 = lane & 15, h = lane >> 4;

  if (tid < BM) {
    const float* lp = lsum + (size_t)(z * 64) * HW + bm + tid;
    float s = 0.f;
#pragma unroll 8
    for (int p = 0; p < 64; ++p) s += lp[(size_t)p * HW];
    lsum_sh[tid] = s;
  }

  f32x4 acc[4][4] = {};
  for (int kt = 0; kt < K; kt += BK) {
    __syncthreads();
#pragma unroll
    for (int s = 0; s < 2; ++s) {
      int cid = tid + s * 256;
      int row = cid >> 2, col = (cid & 3) * 16;
      *(uint4*)(&lA[row * LRB + col]) =
          *(const uint4*)(A + (size_t)(bm + row) * K + kt + col);
      *(uint4*)(&lB[row * LRB + col]) =
          *(const uint4*)(Bt + (size_t)(bn + row) * K + kt + col);
    }
    __syncthreads();
#pragma unroll
    for (int kk = 0; kk < BK; kk += 32) {
      long af[4], bfr[4];
#pragma unroll
      for (int i = 0; i < 4; ++i)
        af[i] = *(const long*)(&lA[(wm + i * 16 + r0) * LRB + kk + h * 8]);
#pragma unroll
      for (int j = 0; j < 4; ++j)
        bfr[j] = *(const long*)(&lB[(wn + j * 16 + r0) * LRB + kk + h * 8]);
#pragma unroll
      for (int i = 0; i < 4; ++i)
#pragma unroll
        for (int j = 0; j < 4; ++j)
          acc[i][j] = __builtin_amdgcn_mfma_f32_16x16x32_fp8_fp8(af[i], bfr[j], acc[i][j], 0, 0, 0);
    }
  }

  u16* C = Ob + (size_t)z * sC;
#pragma unroll
  for (int j = 0; j < 4; ++j) {
    int n = bn + wn + j * 16 + r0;
#pragma unroll
    for (int i = 0; i < 4; ++i) {
      int m0 = bm + wm + i * 16 + h * 4;
#pragma unroll
      for (int r = 0; r < 4; ++r) {
        float inv = 1.0f / lsum_sh[wm + i * 16 + h * 4 + r];
        C[(size_t)(m0 + r) * N + n] = f2bf(acc[i][j][r] * inv);
      }
    }
  }
}

// ---- proj: bf16 m97 GEMM, f32 out + residual ----
__global__ __launch_bounds__(256) void proj97(const u16* __restrict__ A,
                                              const u16* __restrict__ Bt,
                                              const float* __restrict__ bias,
                                              const float* __restrict__ residual,
                                              float* __restrict__ Cout) {
  constexpr int BM = 128, BN = 128, BK = 64;
  const int K = CH, N = CH;
  __shared__ __align__(16) u16 lA[BM * BK];
  __shared__ __align__(16) u16 lB[BN * BK];
  const int tid = threadIdx.x;
  const int lane = tid & 63, wid = tid >> 6;
  const int bm = blockIdx.y * BM, bn = blockIdx.x * BN;
  const int wm = (wid >> 1) * 64, wn = (wid & 1) * 64;
  const int r0 = lane & 15, h = lane >> 4;

  const int srow = lane >> 3, scol = (lane & 7) * 8;
  size_t aoff[4], boff[4];
#pragma unroll
  for (int s = 0; s < 4; ++s) {
    int row = (wid * 4 + s) * 8 + srow;
    aoff[s] = (size_t)(bm + row) * K + scol;
    boff[s] = (size_t)(bn + row) * K + scol;
  }

  f32x4 acc[4][4] = {};
  for (int kt = 0; kt < K; kt += BK) {
    __syncthreads();
#pragma unroll
    for (int s = 0; s < 4; ++s) {
      GLOAD16(A + aoff[s] + kt, &lA[(wid * 4 + s) * 512]);
      GLOAD16(Bt + boff[s] + kt, &lB[(wid * 4 + s) * 512]);
    }
    __syncthreads();
#pragma unroll
    for (int kk = 0; kk < BK; kk += 32) {
      bf16x8 af[4], bfr[4];
#pragma unroll
      for (int i = 0; i < 4; ++i)
        af[i] = *(const bf16x8*)(&lA[(wm + i * 16 + r0) * BK + kk + h * 8]);
#pragma unroll
      for (int j = 0; j < 4; ++j)
        bfr[j] = *(const bf16x8*)(&lB[(wn + j * 16 + r0) * BK + kk + h * 8]);
#pragma unroll
      for (int i = 0; i < 4; ++i)
#pragma unroll
        for (int j = 0; j < 4; ++j)
          acc[i][j] = __builtin_amdgcn_mfma_f32_16x16x32_bf16(af[i], bfr[j], acc[i][j], 0, 0, 0);
    }
  }

#pragma unroll
  for (int j = 0; j < 4; ++j) {
    int n = bn + wn + j * 16 + r0;
    float bvv = bias[n];
#pragma unroll
    for (int i = 0; i < 4; ++i) {
      int m0 = bm + wm + i * 16 + h * 4;
#pragma unroll
      for (int r = 0; r < 4; ++r) {
        size_t idx = (size_t)(m0 + r) * N + n;
        Cout[idx] = acc[i][j][r] + bvv + residual[idx];
      }
    }
  }
}

extern "C" void kernel_launch(void* const* d_in, const int* in_sizes, int n_in,
                              void* d_out, int out_size, void* d_ws, size_t ws_size,
                              hipStream_t stream) {
  (void)in_sizes; (void)n_in; (void)out_size;
  const float* x     = (const float*)d_in[0];
  const float* gamma = (const float*)d_in[1];
  const float* beta  = (const float*)d_in[2];
  const float* Wq    = (const float*)d_in[3];
  const float* bq    = (const float*)d_in[4];
  const float* Wk    = (const float*)d_in[5];
  const float* bk    = (const float*)d_in[6];
  const float* Wv    = (const float*)d_in[7];
  const float* bv    = (const float*)d_in[8];
  const float* Wp    = (const float*)d_in[9];
  const float* bp    = (const float*)d_in[10];
  float* out = (float*)d_out;

  char* ws = (char*)d_ws;
  size_t off = 0;
  auto alloc = [&](size_t bytes) -> void* {
    void* p = ws + off;
    off += (bytes + 255) & ~(size_t)255;
    return p;
  };
  const size_t XN  = (size_t)TOKENS * CH * 2;     // 16 MB bf16
  const size_t X8  = (size_t)TOKENS * CH;         // 8 MB fp8
  const size_t WT  = (size_t)CH * CH * 2;         // 0.5 MB
  const size_t S8B = (size_t)HW * HW;             // 16.8 MB fp8 per batch
  const size_t LS  = (size_t)4 * 64 * HW * sizeof(float);  // 4 MB partial rowsums
  const size_t need_all = 1024 * 1024 + LS + 2 * XN + 3 * X8 + 4 * WT + 4 * S8B;
  const bool big = ws_size >= need_all;           // deterministic across calls

  float2* stats    = (float2*)alloc(128 * sizeof(float2));
  float* lsum_part = (float*)alloc(LS);           // [z][64][HW]
  u16* xn   = (u16*)alloc(XN);
  u16* Ob   = (u16*)alloc(XN);
  u8*  Q8   = (u8*)alloc(X8);    // [B*HW][CH] fp8
  u8*  K8   = (u8*)alloc(X8);
  u8*  V8t  = (u8*)alloc(X8);    // [B][CH][HW] fp8
  u16* Wqkv = (u16*)alloc(3 * WT);  // [Wq^T; Wk^T; Wv^T] stacked along rows
  u16* WpT  = (u16*)alloc(WT);
  u8*  S8   = (u8*)alloc(big ? 4 * S8B : S8B);    // exp'd scores fp8

  gn_stats<<<128, 256, 0, stream>>>(x, stats);
  gn_apply<<<TOKENS * CH / 8 / 256, 256, 0, stream>>>(x, gamma, beta, stats, xn);
  transpose_w<<<dim3(16, 16, 4), dim3(32, 8), 0, stream>>>(
      Wq, Wk, Wv, Wp, Wqkv, Wqkv + (size_t)CH * CH, Wqkv + 2 * (size_t)CH * CH, WpT);

  qkv97<<<dim3(1536 / 128, TOKENS / 128), 256, 0, stream>>>(
      xn, Wqkv, bq, bk, bv, Q8, K8, V8t);

  const float scl = 0.044194173824159216f;  // 1/sqrt(512)
  if (big) {
    sgemm8<<<dim3(HW / 128, HW / 128, 4), 256, 0, stream>>>(
        Q8, K8, lsum_part, S8, HW, HW, CH, scl,
        (size_t)HW * CH, (size_t)HW * CH, (size_t)HW * HW);
    pv8w<<<dim3(256, 1, 1), 512, 0, stream>>>(S8, V8t, lsum_part, Ob);
  } else {
    for (int b = 0; b < 4; ++b) {
      sgemm8<<<dim3(HW / 128, HW / 128, 1), 256, 0, stream>>>(
          Q8 + (size_t)b * HW * CH, K8 + (size_t)b * HW * CH,
          lsum_part + (size_t)b * 64 * HW, S8, HW, HW, CH, scl, 0, 0, 0);
      pv8<<<dim3(4, 32, 1), 256, 0, stream>>>(
          S8, V8t + (size_t)b * CH * HW, lsum_part + (size_t)b * 64 * HW,
          Ob + (size_t)b * HW * CH, HW, CH, HW, 0, 0, 0);
    }
  }

  proj97<<<dim3(CH / 128, TOKENS / 128), 256, 0, stream>>>(Ob, WpT, bp, x, out);
}

// Round 10
// 201.175 us; speedup vs baseline: 1.3524x; 1.2800x over previous
//
#include <hip/hip_runtime.h>

typedef unsigned short u16;
typedef unsigned char u8;
typedef short bf16x8 __attribute__((ext_vector_type(8)));
typedef float f32x4 __attribute__((ext_vector_type(4)));
typedef int i32x8 __attribute__((ext_vector_type(8)));

#define CH 512
#define HW 4096
#define TOKENS 16384
#define NGRP 32

__device__ __forceinline__ u16 f2bf(float f) {
  unsigned u = __float_as_uint(f);
  u += 0x7fffu + ((u >> 16) & 1u);   // round-nearest-even
  return (u16)(u >> 16);
}
__device__ __forceinline__ float bf2f(u16 h) {
  return __uint_as_float(((unsigned)h) << 16);
}
__device__ __forceinline__ u8 f2fp8(float f) {   // OCP e4m3fn, RNE+sat
  return (u8)(__builtin_amdgcn_cvt_pk_fp8_f32(f, f, 0, false) & 0xff);
}
__device__ __forceinline__ unsigned f2fp8x4(float a, float b, float c, float d) {
  int lo = __builtin_amdgcn_cvt_pk_fp8_f32(a, b, 0, false);
  return (unsigned)__builtin_amdgcn_cvt_pk_fp8_f32(c, d, lo, true);
}

// async global->LDS, 16B per lane; lds base must be wave-uniform (HW scatters lane*16)
#define GLOAD16(gp, lp)                                                        \
  __builtin_amdgcn_global_load_lds(                                            \
      (const __attribute__((address_space(1))) unsigned int*)(const void*)(gp),\
      (__attribute__((address_space(3))) unsigned int*)(void*)(lp), 16, 0, 0)

// ---------------- GroupNorm stats: one block per (b,g) ----------------
__global__ void gn_stats(const float* __restrict__ x, float2* __restrict__ stats) {
  int bg = blockIdx.x;              // 0..127
  int b = bg >> 5, g = bg & 31;
  const float* base = x + (size_t)b * HW * CH + g * 16;
  float s = 0.f, s2 = 0.f;
  for (int p = threadIdx.x; p < HW; p += 256) {
    const float4* row = (const float4*)(base + (size_t)p * CH);
#pragma unroll
    for (int q = 0; q < 4; ++q) {
      float4 v = row[q];
      s += v.x + v.y + v.z + v.w;
      s2 += v.x * v.x + v.y * v.y + v.z * v.z + v.w * v.w;
    }
  }
#pragma unroll
  for (int o = 32; o; o >>= 1) { s += __shfl_down(s, o); s2 += __shfl_down(s2, o); }
  __shared__ float rs[4], rs2[4];
  int wid = threadIdx.x >> 6, lane = threadIdx.x & 63;
  if (lane == 0) { rs[wid] = s; rs2[wid] = s2; }
  __syncthreads();
  if (threadIdx.x == 0) {
    float S = rs[0] + rs[1] + rs[2] + rs[3];
    float S2 = rs2[0] + rs2[1] + rs2[2] + rs2[3];
    float mean = S * (1.f / 65536.f);
    float var = S2 * (1.f / 65536.f) - mean * mean;
    stats[bg] = make_float2(mean, rsqrtf(var + 1e-5f));
  }
}

// ---------------- GroupNorm apply -> xn (bf16) ----------------
__global__ void gn_apply(const float* __restrict__ x, const float* __restrict__ gamma,
                         const float* __restrict__ beta, const float2* __restrict__ stats,
                         u16* __restrict__ xn) {
  size_t i = (size_t)blockIdx.x * blockDim.x + threadIdx.x;  // chunk of 8 elems
  size_t e0 = i * 8;
  int c = (int)(e0 & (CH - 1));
  size_t t = e0 >> 9;
  int b = (int)(t >> 12);
  float2 st = stats[b * NGRP + (c >> 4)];
  float4 v0 = *(const float4*)(x + t * CH + c);
  float4 v1 = *(const float4*)(x + t * CH + c + 4);
  float4 g0 = *(const float4*)(gamma + c);
  float4 g1 = *(const float4*)(gamma + c + 4);
  float4 b0 = *(const float4*)(beta + c);
  float4 b1 = *(const float4*)(beta + c + 4);
  float o[8];
  o[0] = (v0.x - st.x) * st.y * g0.x + b0.x;
  o[1] = (v0.y - st.x) * st.y * g0.y + b0.y;
  o[2] = (v0.z - st.x) * st.y * g0.z + b0.z;
  o[3] = (v0.w - st.x) * st.y * g0.w + b0.w;
  o[4] = (v1.x - st.x) * st.y * g1.x + b1.x;
  o[5] = (v1.y - st.x) * st.y * g1.y + b1.y;
  o[6] = (v1.z - st.x) * st.y * g1.z + b1.z;
  o[7] = (v1.w - st.x) * st.y * g1.w + b1.w;
  union { u16 us[8]; uint4 q; } pk;
#pragma unroll
  for (int k = 0; k < 8; ++k) pk.us[k] = f2bf(o[k]);
  *(uint4*)(xn + e0) = pk.q;
}

// ---------------- transpose 512x512 weights fp32 -> bf16 (T[d][c] = W[c][d]) ----------------
__global__ void transpose_w(const float* __restrict__ W0, const float* __restrict__ W1,
                            const float* __restrict__ W2, const float* __restrict__ W3,
                            u16* __restrict__ T0, u16* __restrict__ T1,
                            u16* __restrict__ T2, u16* __restrict__ T3) {
  const float* W; u16* T;
  switch (blockIdx.z) {
    case 0: W = W0; T = T0; break;
    case 1: W = W1; T = T1; break;
    case 2: W = W2; T = T2; break;
    default: W = W3; T = T3; break;
  }
  __shared__ float tile[32][33];
  int tx = threadIdx.x, ty = threadIdx.y;
  int x0 = blockIdx.x * 32, y0 = blockIdx.y * 32;
#pragma unroll
  for (int r = 0; r < 32; r += 8) tile[ty + r][tx] = W[(size_t)(y0 + ty + r) * CH + x0 + tx];
  __syncthreads();
#pragma unroll
  for (int r = 0; r < 32; r += 8) T[(size_t)(x0 + ty + r) * CH + y0 + tx] = f2bf(tile[tx][ty + r]);
}

// ---- QKV: bf16 m97 GEMM (global_load_lds), epilogue -> fp8 Q8,K8 rowmajor + V8t transposed ----
__global__ __launch_bounds__(256) void qkv97(const u16* __restrict__ A,
                                             const u16* __restrict__ Bt,
                                             const float* __restrict__ bq,
                                             const float* __restrict__ bk,
                                             const float* __restrict__ bv,
                                             u8* __restrict__ Q8, u8* __restrict__ K8,
                                             u8* __restrict__ V8t) {
  constexpr int BM = 128, BN = 128, BK = 64;
  const int K = CH;
  __shared__ __align__(16) u16 lA[BM * BK];
  __shared__ __align__(16) u16 lB[BN * BK];
  const int tid = threadIdx.x;
  const int lane = tid & 63, wid = tid >> 6;
  const int bm = blockIdx.y * BM, bn = blockIdx.x * BN;
  const int wm = (wid >> 1) * 64, wn = (wid & 1) * 64;
  const int r0 = lane & 15, h = lane >> 4;

  const int srow = lane >> 3, scol = (lane & 7) * 8;
  size_t aoff[4], boff[4];
#pragma unroll
  for (int s = 0; s < 4; ++s) {
    int row = (wid * 4 + s) * 8 + srow;
    aoff[s] = (size_t)(bm + row) * K + scol;
    boff[s] = (size_t)(bn + row) * K + scol;
  }

  f32x4 acc[4][4] = {};
  for (int kt = 0; kt < K; kt += BK) {
    __syncthreads();
#pragma unroll
    for (int s = 0; s < 4; ++s) {
      GLOAD16(A + aoff[s] + kt, &lA[(wid * 4 + s) * 512]);
      GLOAD16(Bt + boff[s] + kt, &lB[(wid * 4 + s) * 512]);
    }
    __syncthreads();
#pragma unroll
    for (int kk = 0; kk < BK; kk += 32) {
      bf16x8 af[4], bfr[4];
#pragma unroll
      for (int i = 0; i < 4; ++i)
        af[i] = *(const bf16x8*)(&lA[(wm + i * 16 + r0) * BK + kk + h * 8]);
#pragma unroll
      for (int j = 0; j < 4; ++j)
        bfr[j] = *(const bf16x8*)(&lB[(wn + j * 16 + r0) * BK + kk + h * 8]);
#pragma unroll
      for (int i = 0; i < 4; ++i)
#pragma unroll
        for (int j = 0; j < 4; ++j)
          acc[i][j] = __builtin_amdgcn_mfma_f32_16x16x32_bf16(af[i], bfr[j], acc[i][j], 0, 0, 0);
    }
  }

#pragma unroll
  for (int j = 0; j < 4; ++j) {
    int n = bn + wn + j * 16 + r0;
    int nn = n & 511, ch = n >> 9;
    float bvv = ch == 0 ? bq[nn] : ch == 1 ? bk[nn] : bv[nn];
#pragma unroll
    for (int i = 0; i < 4; ++i) {
      int m0 = bm + wm + i * 16 + h * 4;
      float v[4];
#pragma unroll
      for (int r = 0; r < 4; ++r) v[r] = acc[i][j][r] + bvv;
      if (ch == 2) {                  // V: transposed fp8 [bb][CH][HW], pack 4 rows
        int bb = m0 >> 12, tl = m0 & (HW - 1);
        *(unsigned*)(V8t + ((size_t)bb * CH + nn) * HW + tl) =
            f2fp8x4(v[0], v[1], v[2], v[3]);
      } else {
        u8* P = ch == 0 ? Q8 : K8;
#pragma unroll
        for (int r = 0; r < 4; ++r) P[(size_t)(m0 + r) * CH + nn] = f2fp8(v[r]);
      }
    }
  }
}

// ---- MX-fp8 K=128 GEMM, m97-style single-buffer gload_lds, 128x128 tile, BK=128 ----
// mfma_scale_f32_16x16x128_f8f6f4 with unit scales (E8M0 127 -> x1.0): numerics == fp8.
// LDS rows 128B; swizzle: 16B-granule ^= (row&7), applied on global SOURCE (pre-swizzled
// lane col) + on frag READ (involution; gload_lds dest stays linear).
// MODE 5: S = fp8(exp(scale*Q K^T)) + partial rowsums -> lsum_out[(z*64+bx*2+half)*HW+row]
// MODE 4: O = (S V^T)/rowsum (bf16 out); XCD-swizzled 1-D grid when gridDim.y==1
template <int MODE>
__global__ __launch_bounds__(256) void gemm8mx(const u8* __restrict__ A,
                                               const u8* __restrict__ Bt,
                                               const float* __restrict__ lsum_in,
                                               float* __restrict__ lsum_out,
                                               void* __restrict__ Cout,
                                               int N, int K, float scale,
                                               size_t sA, size_t sB, size_t sC) {
  constexpr int BK = 128;
  __shared__ __align__(16) u8 lA[128 * BK];
  __shared__ __align__(16) u8 lB[128 * BK];
  __shared__ float lsum_sh[(MODE == 4) ? 128 : 1];

  int bm, bn, z;
  if constexpr (MODE == 4) {
    if (gridDim.y == 1) {             // big path: 512 blocks, XCD-chunked swizzle
      int p = blockIdx.x;
      int xcd = p & 7, j = p >> 3;    // j: 0..63 per XCD
      int xi = j & 3;                 // 4 consecutive same-XCD blocks share m-panel
      int mp = xcd * 16 + (j >> 2);   // global m-panel 0..127
      bn = xi * 128; bm = (mp & 31) * 128; z = mp >> 5;
    } else {
      z = blockIdx.z; bm = blockIdx.y * 128; bn = blockIdx.x * 128;
    }
  } else {
    z = blockIdx.z; bm = blockIdx.y * 128; bn = blockIdx.x * 128;
  }
  A += (size_t)z * sA;
  Bt += (size_t)z * sB;

  const int tid = threadIdx.x, lane = tid & 63, wid = tid >> 6;
  const int wm = (wid >> 1) * 64, wn = (wid & 1) * 64;
  const int r0 = lane & 15, h = lane >> 4;

  if constexpr (MODE == 4) {
    // pre-pass: true row sums = sum of 64 partials per row
    if (tid < 128) {
      const float* lp = lsum_in + (size_t)(z * 64) * HW + bm + tid;
      float s = 0.f;
#pragma unroll 8
      for (int p = 0; p < 64; ++p) s += lp[(size_t)p * HW];
      lsum_sh[tid] = s;
    }
  }

  // staging: wave stages 32 rows x 128B per operand per K-step (4 GLOADs each).
  // lane covers (srow = lane>>3, granule = lane&7); source col pre-swizzled.
  const int srow = lane >> 3;
  const int scol = ((lane & 7) * 16) ^ ((srow & 7) << 4);
  size_t aoff[4], boff[4];
#pragma unroll
  for (int s = 0; s < 4; ++s) {
    int row = wid * 32 + s * 8 + srow;
    aoff[s] = (size_t)(bm + row) * K + scol;
    boff[s] = (size_t)(bn + row) * K + scol;
  }

  f32x4 acc[4][4] = {};

  for (int kt = 0; kt < K; kt += BK) {
    __syncthreads();
#pragma unroll
    for (int s = 0; s < 4; ++s) {
      GLOAD16(A + aoff[s] + kt, &lA[(wid * 4 + s) * 1024]);
      GLOAD16(Bt + boff[s] + kt, &lB[(wid * 4 + s) * 1024]);
    }
    __syncthreads();
    i32x8 af[4], bf[4];
#pragma unroll
    for (int i = 0; i < 4; ++i) {
      int row = wm + i * 16 + r0;
      int base = row * BK;
      int sw = (row & 7) << 4;
      uint4 lo = *(const uint4*)(&lA[base + ((h * 32) ^ sw)]);
      uint4 hi = *(const uint4*)(&lA[base + ((h * 32 + 16) ^ sw)]);
      af[i][0] = (int)lo.x; af[i][1] = (int)lo.y; af[i][2] = (int)lo.z; af[i][3] = (int)lo.w;
      af[i][4] = (int)hi.x; af[i][5] = (int)hi.y; af[i][6] = (int)hi.z; af[i][7] = (int)hi.w;
    }
#pragma unroll
    for (int j = 0; j < 4; ++j) {
      int row = wn + j * 16 + r0;
      int base = row * BK;
      int sw = (row & 7) << 4;
      uint4 lo = *(const uint4*)(&lB[base + ((h * 32) ^ sw)]);
      uint4 hi = *(const uint4*)(&lB[base + ((h * 32 + 16) ^ sw)]);
      bf[j][0] = (int)lo.x; bf[j][1] = (int)lo.y; bf[j][2] = (int)lo.z; bf[j][3] = (int)lo.w;
      bf[j][4] = (int)hi.x; bf[j][5] = (int)hi.y; bf[j][6] = (int)hi.z; bf[j][7] = (int)hi.w;
    }
#pragma unroll
    for (int i = 0; i < 4; ++i)
#pragma unroll
      for (int j = 0; j < 4; ++j)
        acc[i][j] = __builtin_amdgcn_mfma_scale_f32_16x16x128_f8f6f4(
            af[i], bf[j], acc[i][j], 0, 0, 0, 127, 0, 127);
  }

  // epilogue: D layout col(n)=lane&15, row=(lane>>4)*4+r
  if constexpr (MODE == 5) {
    u8* C = (u8*)Cout + (size_t)z * sC;
    float* lp = lsum_out + (size_t)(z * 64 + blockIdx.x * 2 + (wid & 1)) * HW;
#pragma unroll
    for (int i = 0; i < 4; ++i) {
      int m0 = bm + wm + i * 16 + h * 4;
      float rs[4] = {0.f, 0.f, 0.f, 0.f};
#pragma unroll
      for (int j = 0; j < 4; ++j) {
        int n = bn + wn + j * 16 + r0;
#pragma unroll
        for (int r = 0; r < 4; ++r) {
          float e = __expf(acc[i][j][r] * scale);
          rs[r] += e;
          C[(size_t)(m0 + r) * N + n] = f2fp8(e);
        }
      }
#pragma unroll
      for (int r = 0; r < 4; ++r) {
#pragma unroll
        for (int w = 1; w < 16; w <<= 1) rs[r] += __shfl_xor(rs[r], w);
        if (r0 == 0) lp[m0 + r] = rs[r];
      }
    }
  } else {
    u16* C = (u16*)Cout + (size_t)z * sC;
#pragma unroll
    for (int j = 0; j < 4; ++j) {
      int n = bn + wn + j * 16 + r0;
#pragma unroll
      for (int i = 0; i < 4; ++i) {
        int m0 = bm + wm + i * 16 + h * 4;
#pragma unroll
        for (int r = 0; r < 4; ++r) {
          float inv = 1.0f / lsum_sh[wm + i * 16 + h * 4 + r];
          C[(size_t)(m0 + r) * N + n] = f2bf(acc[i][j][r] * inv);
        }
      }
    }
  }
}

// ---- S-GEMM fp8 fallback (R6-proven, reg-staged) for small-ws path ----
__global__ __launch_bounds__(256) void sgemm8(const u8* __restrict__ A,
                                              const u8* __restrict__ Bt,
                                              float* __restrict__ lsum,
                                              u8* __restrict__ S8,
                                              int M, int N, int K, float scale,
                                              size_t sA, size_t sB, size_t sC) {
  constexpr int BM = 128, BN = 128, BK = 64, LRB = 80;
  __shared__ __align__(16) u8 lA[BM * LRB];
  __shared__ __align__(16) u8 lB[BN * LRB];
  const int z = blockIdx.z;
  A += (size_t)z * sA;
  Bt += (size_t)z * sB;
  const int tid = threadIdx.x;
  const int lane = tid & 63, wid = tid >> 6;
  const int bm = blockIdx.y * BM, bn = blockIdx.x * BN;
  const int wm = (wid >> 1) * 64, wn = (wid & 1) * 64;
  const int r0 = lane & 15, h = lane >> 4;

  f32x4 acc[4][4] = {};
  for (int kt = 0; kt < K; kt += BK) {
    __syncthreads();
#pragma unroll
    for (int s = 0; s < 2; ++s) {
      int cid = tid + s * 256;
      int row = cid >> 2, col = (cid & 3) * 16;
      *(uint4*)(&lA[row * LRB + col]) =
          *(const uint4*)(A + (size_t)(bm + row) * K + kt + col);
      *(uint4*)(&lB[row * LRB + col]) =
          *(const uint4*)(Bt + (size_t)(bn + row) * K + kt + col);
    }
    __syncthreads();
#pragma unroll
    for (int kk = 0; kk < BK; kk += 32) {
      long af[4], bfr[4];
#pragma unroll
      for (int i = 0; i < 4; ++i)
        af[i] = *(const long*)(&lA[(wm + i * 16 + r0) * LRB + kk + h * 8]);
#pragma unroll
      for (int j = 0; j < 4; ++j)
        bfr[j] = *(const long*)(&lB[(wn + j * 16 + r0) * LRB + kk + h * 8]);
#pragma unroll
      for (int i = 0; i < 4; ++i)
#pragma unroll
        for (int j = 0; j < 4; ++j)
          acc[i][j] = __builtin_amdgcn_mfma_f32_16x16x32_fp8_fp8(af[i], bfr[j], acc[i][j], 0, 0, 0);
    }
  }

  u8* C = S8 + (size_t)z * sC;
  float* lp = lsum + (size_t)(z * 64 + blockIdx.x * 2 + (wid & 1)) * HW;
#pragma unroll
  for (int i = 0; i < 4; ++i) {
    int m0 = bm + wm + i * 16 + h * 4;
    float rs[4] = {0.f, 0.f, 0.f, 0.f};
#pragma unroll
    for (int j = 0; j < 4; ++j) {
      int n = bn + wn + j * 16 + r0;
#pragma unroll
      for (int r = 0; r < 4; ++r) {
        float e = __expf(acc[i][j][r] * scale);
        rs[r] += e;
        C[(size_t)(m0 + r) * N + n] = f2fp8(e);
      }
    }
#pragma unroll
    for (int r = 0; r < 4; ++r) {
#pragma unroll
      for (int w = 1; w < 16; w <<= 1) rs[r] += __shfl_xor(rs[r], w);
      if (r0 == 0) lp[m0 + r] = rs[r];
    }
  }
}

// ---- PV fp8 fallback (R6-proven, reg-staged) for small-ws path ----
__global__ __launch_bounds__(256) void pv8(const u8* __restrict__ A,
                                           const u8* __restrict__ Bt,
                                           const float* __restrict__ lsum,
                                           u16* __restrict__ Ob,
                                           int M, int N, int K,
                                           size_t sA, size_t sB, size_t sC) {
  constexpr int BM = 128, BN = 128, BK = 64, LRB = 80;
  __shared__ __align__(16) u8 lA[BM * LRB];
  __shared__ __align__(16) u8 lB[BN * LRB];
  __shared__ float lsum_sh[BM];

  int bm, bn, z;
  z = blockIdx.z; bm = blockIdx.y * BM; bn = blockIdx.x * BN;
  A += (size_t)z * sA;
  Bt += (size_t)z * sB;
  const int tid = threadIdx.x;
  const int lane = tid & 63, wid = tid >> 6;
  const int wm = (wid >> 1) * 64, wn = (wid & 1) * 64;
  const int r0 = lane & 15, h = lane >> 4;

  if (tid < BM) {
    const float* lp = lsum + (size_t)(z * 64) * HW + bm + tid;
    float s = 0.f;
#pragma unroll 8
    for (int p = 0; p < 64; ++p) s += lp[(size_t)p * HW];
    lsum_sh[tid] = s;
  }

  f32x4 acc[4][4] = {};
  for (int kt = 0; kt < K; kt += BK) {
    __syncthreads();
#pragma unroll
    for (int s = 0; s < 2; ++s) {
      int cid = tid + s * 256;
      int row = cid >> 2, col = (cid & 3) * 16;
      *(uint4*)(&lA[row * LRB + col]) =
          *(const uint4*)(A + (size_t)(bm + row) * K + kt + col);
      *(uint4*)(&lB[row * LRB + col]) =
          *(const uint4*)(Bt + (size_t)(bn + row) * K + kt + col);
    }
    __syncthreads();
#pragma unroll
    for (int kk = 0; kk < BK; kk += 32) {
      long af[4], bfr[4];
#pragma unroll
      for (int i = 0; i < 4; ++i)
        af[i] = *(const long*)(&lA[(wm + i * 16 + r0) * LRB + kk + h * 8]);
#pragma unroll
      for (int j = 0; j < 4; ++j)
        bfr[j] = *(const long*)(&lB[(wn + j * 16 + r0) * LRB + kk + h * 8]);
#pragma unroll
      for (int i = 0; i < 4; ++i)
#pragma unroll
        for (int j = 0; j < 4; ++j)
          acc[i][j] = __builtin_amdgcn_mfma_f32_16x16x32_fp8_fp8(af[i], bfr[j], acc[i][j], 0, 0, 0);
    }
  }

  u16* C = Ob + (size_t)z * sC;
#pragma unroll
  for (int j = 0; j < 4; ++j) {
    int n = bn + wn + j * 16 + r0;
#pragma unroll
    for (int i = 0; i < 4; ++i) {
      int m0 = bm + wm + i * 16 + h * 4;
#pragma unroll
      for (int r = 0; r < 4; ++r) {
        float inv = 1.0f / lsum_sh[wm + i * 16 + h * 4 + r];
        C[(size_t)(m0 + r) * N + n] = f2bf(acc[i][j][r] * inv);
      }
    }
  }
}

// ---- proj: bf16 m97 GEMM, f32 out + residual ----
__global__ __launch_bounds__(256) void proj97(const u16* __restrict__ A,
                                              const u16* __restrict__ Bt,
                                              const float* __restrict__ bias,
                                              const float* __restrict__ residual,
                                              float* __restrict__ Cout) {
  constexpr int BM = 128, BN = 128, BK = 64;
  const int K = CH, N = CH;
  __shared__ __align__(16) u16 lA[BM * BK];
  __shared__ __align__(16) u16 lB[BN * BK];
  const int tid = threadIdx.x;
  const int lane = tid & 63, wid = tid >> 6;
  const int bm = blockIdx.y * BM, bn = blockIdx.x * BN;
  const int wm = (wid >> 1) * 64, wn = (wid & 1) * 64;
  const int r0 = lane & 15, h = lane >> 4;

  const int srow = lane >> 3, scol = (lane & 7) * 8;
  size_t aoff[4], boff[4];
#pragma unroll
  for (int s = 0; s < 4; ++s) {
    int row = (wid * 4 + s) * 8 + srow;
    aoff[s] = (size_t)(bm + row) * K + scol;
    boff[s] = (size_t)(bn + row) * K + scol;
  }

  f32x4 acc[4][4] = {};
  for (int kt = 0; kt < K; kt += BK) {
    __syncthreads();
#pragma unroll
    for (int s = 0; s < 4; ++s) {
      GLOAD16(A + aoff[s] + kt, &lA[(wid * 4 + s) * 512]);
      GLOAD16(Bt + boff[s] + kt, &lB[(wid * 4 + s) * 512]);
    }
    __syncthreads();
#pragma unroll
    for (int kk = 0; kk < BK; kk += 32) {
      bf16x8 af[4], bfr[4];
#pragma unroll
      for (int i = 0; i < 4; ++i)
        af[i] = *(const bf16x8*)(&lA[(wm + i * 16 + r0) * BK + kk + h * 8]);
#pragma unroll
      for (int j = 0; j < 4; ++j)
        bfr[j] = *(const bf16x8*)(&lB[(wn + j * 16 + r0) * BK + kk + h * 8]);
#pragma unroll
      for (int i = 0; i < 4; ++i)
#pragma unroll
        for (int j = 0; j < 4; ++j)
          acc[i][j] = __builtin_amdgcn_mfma_f32_16x16x32_bf16(af[i], bfr[j], acc[i][j], 0, 0, 0);
    }
  }

#pragma unroll
  for (int j = 0; j < 4; ++j) {
    int n = bn + wn + j * 16 + r0;
    float bvv = bias[n];
#pragma unroll
    for (int i = 0; i < 4; ++i) {
      int m0 = bm + wm + i * 16 + h * 4;
#pragma unroll
      for (int r = 0; r < 4; ++r) {
        size_t idx = (size_t)(m0 + r) * N + n;
        Cout[idx] = acc[i][j][r] + bvv + residual[idx];
      }
    }
  }
}

extern "C" void kernel_launch(void* const* d_in, const int* in_sizes, int n_in,
                              void* d_out, int out_size, void* d_ws, size_t ws_size,
                              hipStream_t stream) {
  (void)in_sizes; (void)n_in; (void)out_size;
  const float* x     = (const float*)d_in[0];
  const float* gamma = (const float*)d_in[1];
  const float* beta  = (const float*)d_in[2];
  const float* Wq    = (const float*)d_in[3];
  const float* bq    = (const float*)d_in[4];
  const float* Wk    = (const float*)d_in[5];
  const float* bk    = (const float*)d_in[6];
  const float* Wv    = (const float*)d_in[7];
  const float* bv    = (const float*)d_in[8];
  const float* Wp    = (const float*)d_in[9];
  const float* bp    = (const float*)d_in[10];
  float* out = (float*)d_out;

  char* ws = (char*)d_ws;
  size_t off = 0;
  auto alloc = [&](size_t bytes) -> void* {
    void* p = ws + off;
    off += (bytes + 255) & ~(size_t)255;
    return p;
  };
  const size_t XN  = (size_t)TOKENS * CH * 2;     // 16 MB bf16
  const size_t X8  = (size_t)TOKENS * CH;         // 8 MB fp8
  const size_t WT  = (size_t)CH * CH * 2;         // 0.5 MB
  const size_t S8B = (size_t)HW * HW;             // 16.8 MB fp8 per batch
  const size_t LS  = (size_t)4 * 64 * HW * sizeof(float);  // 4 MB partial rowsums
  const size_t need_all = 1024 * 1024 + LS + 2 * XN + 3 * X8 + 4 * WT + 4 * S8B;
  const bool big = ws_size >= need_all;           // deterministic across calls

  float2* stats    = (float2*)alloc(128 * sizeof(float2));
  float* lsum_part = (float*)alloc(LS);           // [z][64][HW]
  u16* xn   = (u16*)alloc(XN);
  u16* Ob   = (u16*)alloc(XN);
  u8*  Q8   = (u8*)alloc(X8);    // [B*HW][CH] fp8
  u8*  K8   = (u8*)alloc(X8);
  u8*  V8t  = (u8*)alloc(X8);    // [B][CH][HW] fp8
  u16* Wqkv = (u16*)alloc(3 * WT);  // [Wq^T; Wk^T; Wv^T] stacked along rows
  u16* WpT  = (u16*)alloc(WT);
  u8*  S8   = (u8*)alloc(big ? 4 * S8B : S8B);    // exp'd scores fp8

  gn_stats<<<128, 256, 0, stream>>>(x, stats);
  gn_apply<<<TOKENS * CH / 8 / 256, 256, 0, stream>>>(x, gamma, beta, stats, xn);
  transpose_w<<<dim3(16, 16, 4), dim3(32, 8), 0, stream>>>(
      Wq, Wk, Wv, Wp, Wqkv, Wqkv + (size_t)CH * CH, Wqkv + 2 * (size_t)CH * CH, WpT);

  qkv97<<<dim3(1536 / 128, TOKENS / 128), 256, 0, stream>>>(
      xn, Wqkv, bq, bk, bv, Q8, K8, V8t);

  const float scl = 0.044194173824159216f;  // 1/sqrt(512)
  if (big) {
    gemm8mx<5><<<dim3(32, 32, 4), 256, 0, stream>>>(
        Q8, K8, nullptr, lsum_part, S8, HW, CH, scl,
        (size_t)HW * CH, (size_t)HW * CH, (size_t)HW * HW);
    gemm8mx<4><<<dim3(512, 1, 1), 256, 0, stream>>>(
        S8, V8t, lsum_part, nullptr, Ob, CH, HW, 1.0f,
        (size_t)HW * HW, (size_t)CH * HW, (size_t)HW * CH);
  } else {
    for (int b = 0; b < 4; ++b) {
      sgemm8<<<dim3(HW / 128, HW / 128, 1), 256, 0, stream>>>(
          Q8 + (size_t)b * HW * CH, K8 + (size_t)b * HW * CH,
          lsum_part + (size_t)b * 64 * HW, S8, HW, HW, CH, scl, 0, 0, 0);
      pv8<<<dim3(4, 32, 1), 256, 0, stream>>>(
          S8, V8t + (size_t)b * CH * HW, lsum_part + (size_t)b * 64 * HW,
          Ob + (size_t)b * HW * CH, HW, CH, HW, 0, 0, 0);
    }
  }

  proj97<<<dim3(CH / 128, TOKENS / 128), 256, 0, stream>>>(Ob, WpT, bp, x, out);
}